// Round 12
// baseline (92.518 us; speedup 1.0000x reference)
//
#include <hip/hip_runtime.h>
#include <hip/hip_bf16.h>
#include <stdint.h>

// LinearEnsemble: out[b,m,o] = sum_i W[m,o,i]*x[b,i] + bias[m,o]
// == C[4096x8192] = x[4096x1024] * Wbig^T (+bias), Wbig = [8192x1024] row-major.
// v13: v12 with the CORRECT m201 staging map + guard depth (the only change).
//   v12's map staged kt+1's last half 1 phase before the guard -> VMCNT(2) =
//   near-drain every K-tile. Correct map (from read-completion audit):
//     P1: stage (kt+1) Ah1 into buf D^1   [D^1's A-H1 reads retired (kt-1).P3]
//     P3: stage (kt+2) Bh0 into buf D     [D's B fully read after P2]
//     P4: stage (kt+2) Bh1 + Ah0 into D   [D's A fully read after P3]
//   -> every half-tile has >=3 phases to land; P4 guard = VMCNT(6)
//      (in flight: kt+2's Bh0,Bh1,Ah0 = 3 half-tiles x 2 loads, m201's formula).
//   Prologue: kt0 all 4 halves + kt1 {Ah0,Bh0,Bh1} (14 loads), VMCNT(6), bar.
//   Tail: VMCNT(6) thru kt=NT-3; VMCNT(0) at NT-2; none at NT-1.

typedef __bf16 bf16;
typedef __attribute__((ext_vector_type(8))) __bf16 bf16x8;
typedef __attribute__((ext_vector_type(4))) float f32x4;

#define GAS __attribute__((address_space(1)))
#define LAS __attribute__((address_space(3)))

__device__ __forceinline__ void gload_lds16(void* lds, const void* g) {
    __builtin_amdgcn_global_load_lds((const GAS uint32_t*)g, (LAS uint32_t*)lds, 16, 0, 0);
}

__device__ __forceinline__ void wg_barrier() {
    asm volatile("" ::: "memory");
    __builtin_amdgcn_s_barrier();
    asm volatile("" ::: "memory");
}

#define VMCNT(n)   asm volatile("s_waitcnt vmcnt(" #n ")" ::: "memory")
#define LGKM0      asm volatile("s_waitcnt lgkmcnt(0)" ::: "memory")
#define SCHED_FENCE() __builtin_amdgcn_sched_barrier(0)

template<int OFF>
__device__ __forceinline__ bf16x8 ds_read_frag(const char* p) {
    f32x4 r;
    asm volatile("ds_read_b128 %0, %1 offset:%2"
                 : "=v"(r)
                 : "v"((const LAS char*)p), "i"(OFF));
    return __builtin_bit_cast(bf16x8, r);
}

#define MFMA(A, B, C) __builtin_amdgcn_mfma_f32_16x16x32_bf16(A, B, C, 0, 0, 0)

__device__ __forceinline__ uint4 pack8(float4 a, float4 b) {
    union { bf16 t[8]; uint4 v; } u;
    u.t[0] = (bf16)a.x; u.t[1] = (bf16)a.y; u.t[2] = (bf16)a.z; u.t[3] = (bf16)a.w;
    u.t[4] = (bf16)b.x; u.t[5] = (bf16)b.y; u.t[6] = (bf16)b.z; u.t[7] = (bf16)b.w;
    return u.v;
}

// ---------------- fused f32 -> bf16 convert for x and W (one launch) ----------------
__global__ void LE_cvt2_kernel(const float* __restrict__ x, const float* __restrict__ w,
                               bf16* __restrict__ out, int nx, int ntot) {
    const int stride = gridDim.x * blockDim.x * 8;
    for (int i = (blockIdx.x * blockDim.x + threadIdx.x) * 8; i < ntot; i += stride) {
        const float* s = (i < nx) ? (x + i) : (w + (i - nx));
        float4 f0 = *(const float4*)s;
        float4 f1 = *(const float4*)(s + 4);
        *(uint4*)(out + i) = pack8(f0, f1);
    }
}

// ---------------- 256x256, BK=64, 8-phase (2 K-tiles/iter) MFMA GEMM ----------------
// 512 threads = 8 waves (2x4), wave owns 128x64 (8x4 frags of 16x16).
// LDS 128 KB: A[buf][half][128*64] at buf*32768 + half*16384; B likewise at +65536.
__global__ __launch_bounds__(512, 2) void LE_gemm_p8_kernel(const bf16* __restrict__ A,
                                                            const bf16* __restrict__ B,
                                                            const float* __restrict__ bias,
                                                            float* __restrict__ out) {
    constexpr int K  = 1024;
    constexpr int NT = 16;                 // K / 64 K-tiles
    __shared__ char Lc[131072];

    // XCD band swizzle: 512 blocks, each XCD gets 16 row-tiles x 4 col-tiles.
    const int raw  = blockIdx.x;
    const int xcd  = raw & 7;
    const int idx  = raw >> 3;
    const int trow = idx >> 2;             // 0..15
    const int tcol = xcd * 4 + (idx & 3);  // 0..31

    const int tid  = threadIdx.x;
    const int lane = tid & 63;
    const int w    = tid >> 6;
    const int wr   = w >> 2, wc = w & 3;   // 2 x 4 wave grid
    const int fr   = lane & 15;
    const int fq   = lane >> 4;

    // staging: thread t covers 16 B (granule t&7) of row t>>3 within a 64-row
    // half-tile chunk; source granule pre-swizzled: sg = (t&7)^(row&7).
    const int sg = ((tid & 7) ^ ((tid >> 3) & 7)) * 8;
    const bf16* a_srcb = A + (size_t)(trow * 256 + (tid >> 3)) * K + sg;
    const bf16* b_srcb = B + (size_t)(tcol * 256 + (tid >> 3)) * K + sg;

    // fragment-read pointers: row-local byte = row*128 + pos*16,
    // pos(ks,fq,fr) = (ks*4+fq)^(fr&7); pa0/pb0 = ks0, pa1/pb1 = ks1 (pos^4).
    const int pos0 = fq ^ (fr & 7);
    const int pos1 = pos0 ^ 4;
    const char* pa0 = Lc + wr * 16384 + fr * 128 + pos0 * 16;
    const char* pa1 = Lc + wr * 16384 + fr * 128 + pos1 * 16;
    const char* pb0 = Lc + 65536 + (wc >> 1) * 16384 + (wc & 1) * 8192 + fr * 128 + pos0 * 16;
    const char* pb1 = Lc + 65536 + (wc >> 1) * 16384 + (wc & 1) * 8192 + fr * 128 + pos1 * 16;

    f32x4 acc[8][4];
    const f32x4 zero = {0.f, 0.f, 0.f, 0.f};
#pragma unroll
    for (int mi = 0; mi < 8; ++mi)
#pragma unroll
        for (int ni = 0; ni < 4; ++ni) acc[mi][ni] = zero;

#define STAGE_A(D, H, KT) {                                                        \
        char* d0 = Lc + (D) * 32768 + (H) * 16384 + tid * 16;                      \
        const bf16* s = a_srcb + (size_t)((H) * 128) * K + (KT) * 64;              \
        gload_lds16(d0,        s);                                                 \
        gload_lds16(d0 + 8192, s + (size_t)64 * K); }
#define STAGE_B(D, H, KT) {                                                        \
        char* d0 = Lc + 65536 + (D) * 32768 + (H) * 16384 + tid * 16;              \
        const bf16* s = b_srcb + (size_t)((H) * 128) * K + (KT) * 64;              \
        gload_lds16(d0,        s);                                                 \
        gload_lds16(d0 + 8192, s + (size_t)64 * K); }

    // -------- prologue: kt0 all 4 halves, then kt1 {Ah0,Bh0,Bh1}; VMCNT(6) ----
    STAGE_A(0, 0, 0); STAGE_A(0, 1, 0); STAGE_B(0, 0, 0); STAGE_B(0, 1, 0);
    STAGE_A(1, 0, 1); STAGE_B(1, 0, 1); STAGE_B(1, 1, 1);
    VMCNT(6);          // kt0 landed; kt1's 3 half-tiles stay in flight
    wg_barrier();

    // period = one K-tile (4 phases). D = buf (compile-time), KT runtime.
#define PERIOD(D, KT) {                                                            \
        constexpr int OA = (D) * 32768;                                            \
        constexpr int OB = (D) * 32768;                                            \
        bf16x8 aL[4][2], bL[2][2], aH[4][2], bH[2][2];                             \
        /* ---- P1: read A[mh0] (8) + B[nh0] (4); stage (kt+1) Ah1 [buf D^1];  */  \
        /*         Q(0..3, 0..1)                                               */  \
        aL[0][0] = ds_read_frag<OA + 0>(pa0);                                      \
        aL[1][0] = ds_read_frag<OA + 2048>(pa0);                                   \
        aL[2][0] = ds_read_frag<OA + 4096>(pa0);                                   \
        aL[3][0] = ds_read_frag<OA + 6144>(pa0);                                   \
        aL[0][1] = ds_read_frag<OA + 0>(pa1);                                      \
        aL[1][1] = ds_read_frag<OA + 2048>(pa1);                                   \
        aL[2][1] = ds_read_frag<OA + 4096>(pa1);                                   \
        aL[3][1] = ds_read_frag<OA + 6144>(pa1);                                   \
        bL[0][0] = ds_read_frag<OB + 0>(pb0);                                      \
        bL[1][0] = ds_read_frag<OB + 2048>(pb0);                                   \
        bL[0][1] = ds_read_frag<OB + 0>(pb1);                                      \
        bL[1][1] = ds_read_frag<OB + 2048>(pb1);                                   \
        if ((KT) + 1 < NT) STAGE_A((D) ^ 1, 1, (KT) + 1);                          \
        wg_barrier(); LGKM0; SCHED_FENCE();                                        \
        __builtin_amdgcn_s_setprio(1);                                             \
        _Pragma("unroll")                                                          \
        for (int ks = 0; ks < 2; ++ks)                                             \
            _Pragma("unroll")                                                      \
            for (int mi = 0; mi < 4; ++mi)                                         \
                _Pragma("unroll")                                                  \
                for (int ni = 0; ni < 2; ++ni)                                     \
                    acc[mi][ni] = MFMA(aL[mi][ks], bL[ni][ks], acc[mi][ni]);       \
        __builtin_amdgcn_s_setprio(0);                                             \
        SCHED_FENCE(); wg_barrier();                                               \
        /* ---- P2: read B[nh1] (4); NO stage; Q(0..3, 2..3) (A reused)        */  \
        bH[0][0] = ds_read_frag<OB + 4096>(pb0);                                   \
        bH[1][0] = ds_read_frag<OB + 6144>(pb0);                                   \
        bH[0][1] = ds_read_frag<OB + 4096>(pb1);                                   \
        bH[1][1] = ds_read_frag<OB + 6144>(pb1);                                   \
        wg_barrier(); LGKM0; SCHED_FENCE();                                        \
        __builtin_amdgcn_s_setprio(1);                                             \
        _Pragma("unroll")                                                          \
        for (int ks = 0; ks < 2; ++ks)                                             \
            _Pragma("unroll")                                                      \
            for (int mi = 0; mi < 4; ++mi)                                         \
                _Pragma("unroll")                                                  \
                for (int ni = 0; ni < 2; ++ni)                                     \
                    acc[mi][2 + ni] = MFMA(aL[mi][ks], bH[ni][ks], acc[mi][2 + ni]); \
        __builtin_amdgcn_s_setprio(0);                                             \
        SCHED_FENCE(); wg_barrier();                                               \
        /* ---- P3: read A[mh1] (8); stage (kt+2) Bh0 [buf D: B fully read     */  \
        /*         after P2]; Q(4..7, 2..3) (B reused)                         */  \
        aH[0][0] = ds_read_frag<OA + 8192 + 0>(pa0);                               \
        aH[1][0] = ds_read_frag<OA + 8192 + 2048>(pa0);                            \
        aH[2][0] = ds_read_frag<OA + 8192 + 4096>(pa0);                            \
        aH[3][0] = ds_read_frag<OA + 8192 + 6144>(pa0);                            \
        aH[0][1] = ds_read_frag<OA + 8192 + 0>(pa1);                               \
        aH[1][1] = ds_read_frag<OA + 8192 + 2048>(pa1);                            \
        aH[2][1] = ds_read_frag<OA + 8192 + 4096>(pa1);                            \
        aH[3][1] = ds_read_frag<OA + 8192 + 6144>(pa1);                            \
        if ((KT) + 2 < NT) STAGE_B((D), 0, (KT) + 2);                              \
        wg_barrier(); LGKM0; SCHED_FENCE();                                        \
        __builtin_amdgcn_s_setprio(1);                                             \
        _Pragma("unroll")                                                          \
        for (int ks = 0; ks < 2; ++ks)                                             \
            _Pragma("unroll")                                                      \
            for (int mi = 0; mi < 4; ++mi)                                         \
                _Pragma("unroll")                                                  \
                for (int ni = 0; ni < 2; ++ni)                                     \
                    acc[4 + mi][2 + ni] = MFMA(aH[mi][ks], bH[ni][ks], acc[4 + mi][2 + ni]); \
        __builtin_amdgcn_s_setprio(0);                                             \
        SCHED_FENCE(); wg_barrier();                                               \
        /* ---- P4: no reads; stage (kt+2) Bh1 + Ah0 [buf D: A fully read      */  \
        /*         after P3]; Q(4..7, 0..1); guard VMCNT(6) + closing barrier  */  \
        if ((KT) + 2 < NT) { STAGE_B((D), 1, (KT) + 2); STAGE_A((D), 0, (KT) + 2); } \
        wg_barrier(); SCHED_FENCE();                                               \
        __builtin_amdgcn_s_setprio(1);                                             \
        _Pragma("unroll")                                                          \
        for (int ks = 0; ks < 2; ++ks)                                             \
            _Pragma("unroll")                                                      \
            for (int mi = 0; mi < 4; ++mi)                                         \
                _Pragma("unroll")                                                  \
                for (int ni = 0; ni < 2; ++ni)                                     \
                    acc[4 + mi][ni] = MFMA(aH[mi][ks], bL[ni][ks], acc[4 + mi][ni]); \
        __builtin_amdgcn_s_setprio(0);                                             \
        SCHED_FENCE();                                                             \
        /* guard: kt+1 fully landed; in flight = kt+2's {Bh0,Bh1,Ah0} = 6 */       \
        if ((KT) <= NT - 3)      { VMCNT(6); }                                     \
        else if ((KT) == NT - 2) { VMCNT(0); }                                     \
        wg_barrier();                                                              \
    }

    for (int kt = 0; kt < NT; kt += 2) {
        PERIOD(0, kt);
        PERIOD(1, kt + 1);
    }
#undef PERIOD
#undef STAGE_A
#undef STAGE_B

    // ---------------- epilogue: C = acc + bias[col] ----------------
    const int rowb = trow * 256 + wr * 128;
    const int colb = tcol * 256 + wc * 64;
    float bv[4];
#pragma unroll
    for (int fn = 0; fn < 4; ++fn) bv[fn] = bias[colb + fn * 16 + fr];
#pragma unroll
    for (int fm = 0; fm < 8; ++fm) {
        const int r0 = rowb + fm * 16 + fq * 4;
#pragma unroll
        for (int fn = 0; fn < 4; ++fn) {
            const int c = colb + fn * 16 + fr;
            float* p = out + (size_t)r0 * 8192 + c;
            f32x4 v = acc[fm][fn];
            p[0 * 8192] = v[0] + bv[fn];
            p[1 * 8192] = v[1] + bv[fn];
            p[2 * 8192] = v[2] + bv[fn];
            p[3 * 8192] = v[3] + bv[fn];
        }
    }
}

// ---------------- fallback (no workspace): reg-staged f32 128x128 GEMM ----------------
__global__ __launch_bounds__(256) void LE_gemm_fb_kernel(const float* __restrict__ A,
                                                         const float* __restrict__ B,
                                                         const float* __restrict__ bias,
                                                         float* __restrict__ out) {
    constexpr int K = 1024;
    __shared__ bf16 As[128 * 32];
    __shared__ bf16 Bs[128 * 32];

    const int raw  = blockIdx.x;
    const int xcd  = raw & 7;
    const int idx  = raw >> 3;
    const int trow = idx & 31;
    const int tcol = xcd * 8 + (idx >> 5);

    const int tid  = threadIdx.x;
    const int lane = tid & 63;
    const int w    = tid >> 6;
    const int wr   = w >> 1, wc = w & 1;
    const int fr   = lane & 15;
    const int fq   = lane >> 4;

    f32x4 acc[4][4];
    const f32x4 zero = {0.f, 0.f, 0.f, 0.f};
#pragma unroll
    for (int mi = 0; mi < 4; mi++)
#pragma unroll
        for (int ni = 0; ni < 4; ni++) acc[mi][ni] = zero;

    const float* Ap = A + (size_t)trow * 128 * K;
    const float* Bp = B + (size_t)tcol * 128 * K;
    const int sr = tid >> 1;
    const int sc = (tid & 1) * 16;
    for (int k0 = 0; k0 < K; k0 += 32) {
        const float* pa = Ap + (size_t)sr * K + k0 + sc;
        const float* pb = Bp + (size_t)sr * K + k0 + sc;
        float4 a0 = *(const float4*)(pa + 0);
        float4 a1 = *(const float4*)(pa + 4);
        float4 a2 = *(const float4*)(pa + 8);
        float4 a3 = *(const float4*)(pa + 12);
        float4 b0 = *(const float4*)(pb + 0);
        float4 b1 = *(const float4*)(pb + 4);
        float4 b2 = *(const float4*)(pb + 8);
        float4 b3 = *(const float4*)(pb + 12);
        __syncthreads();
        char* la = (char*)As + sr * 64 + sc * 2;
        char* lb = (char*)Bs + sr * 64 + sc * 2;
        *(uint4*)(la)      = pack8(a0, a1);
        *(uint4*)(la + 16) = pack8(a2, a3);
        *(uint4*)(lb)      = pack8(b0, b1);
        *(uint4*)(lb + 16) = pack8(b2, b3);
        __syncthreads();
        bf16x8 af[4], bfv2[4];
#pragma unroll
        for (int mi = 0; mi < 4; mi++)
            af[mi] = *(const bf16x8*)&As[(wr * 64 + mi * 16 + fr) * 32 + fq * 8];
#pragma unroll
        for (int ni = 0; ni < 4; ni++)
            bfv2[ni] = *(const bf16x8*)&Bs[(wc * 64 + ni * 16 + fr) * 32 + fq * 8];
#pragma unroll
        for (int mi = 0; mi < 4; mi++)
#pragma unroll
            for (int ni = 0; ni < 4; ni++)
                acc[mi][ni] = __builtin_amdgcn_mfma_f32_16x16x32_bf16(af[mi], bfv2[ni],
                                                                      acc[mi][ni], 0, 0, 0);
    }
    __syncthreads();

    const int rowb = trow * 128 + wr * 64;
    const int colb = tcol * 128 + wc * 64;
#pragma unroll
    for (int mi = 0; mi < 4; mi++) {
        const int r0 = rowb + mi * 16 + fq * 4;
#pragma unroll
        for (int ni = 0; ni < 4; ni++) {
            const int c = colb + ni * 16 + fr;
            const float bvv = bias[c];
            float* p = out + (size_t)r0 * 8192 + c;
            f32x4 v = acc[mi][ni];
            p[0 * 8192] = v[0] + bvv;
            p[1 * 8192] = v[1] + bvv;
            p[2 * 8192] = v[2] + bvv;
            p[3 * 8192] = v[3] + bvv;
        }
    }
}

extern "C" void kernel_launch(void* const* d_in, const int* in_sizes, int n_in,
                              void* d_out, int out_size, void* d_ws, size_t ws_size,
                              hipStream_t stream) {
    const float* x    = (const float*)d_in[0];   // [4096, 1024]
    const float* wgt  = (const float*)d_in[1];   // [8, 1024, 1024] == Wbig^T [8192,1024]
    const float* bias = (const float*)d_in[2];   // [8, 1024] == [8192]
    float* out = (float*)d_out;                  // [4096, 8192]

    const size_t NX = (size_t)4096 * 1024;
    const size_t NW = (size_t)8192 * 1024;

    if (ws_size >= (NX + NW) * sizeof(bf16)) {
        bf16* xb = (bf16*)d_ws;
        bf16* wb = xb + NX;
        LE_cvt2_kernel<<<2048, 256, 0, stream>>>(x, wgt, xb, (int)NX, (int)(NX + NW));
        LE_gemm_p8_kernel<<<512, 512, 0, stream>>>(xb, wb, bias, out);
    } else {
        LE_gemm_fb_kernel<<<2048, 256, 0, stream>>>(x, wgt, bias, out);
    }
}